// Round 7
// baseline (715.425 us; speedup 1.0000x reference)
//
#include <hip/hip_runtime.h>
#include <hip/hip_bf16.h>

// DIEN (DIN_V2_Gru_Vec_attGru) forward. B=512, T=200, D=128, H=128.
// Round 7: GRU restructured — 1 thread/col, 128 thr/row, 2 rows per 256-block.
// Zero shuffles (direct b16 LDS writes), h+u in registers, r/u dots share hH
// reads, 2 lgkm-only barriers/step. Weights 192 f16x2 words in VGPRs.

typedef __attribute__((ext_vector_type(8))) short bf16x8;
typedef __attribute__((ext_vector_type(4))) float f32x4;
typedef _Float16 f16x2 __attribute__((ext_vector_type(2)));

#define NC 4
#define TC 50
#define CROWS 25600          // TC*512 rows per chunk
#define CSH 3276800          // CROWS*128 shorts per chunk (rnn1/h1/XhA)

static __device__ __forceinline__ unsigned short f2bf(float f) {
  union { __hip_bfloat16 h; unsigned short u; } v;
  v.h = __float2bfloat16(f);
  return v.u;
}
static __device__ __forceinline__ float bf2f(unsigned short u) {
  union { __hip_bfloat16 h; unsigned short u; } v;
  v.u = u;
  return __bfloat162float(v.h);
}
static __device__ __forceinline__ unsigned short f2h(float f) {
  union { _Float16 h; unsigned short u; } v;
  v.h = (_Float16)f;
  return v.u;
}
static __device__ __forceinline__ float h2f(unsigned short u) {
  union { unsigned short u; _Float16 h; } v;
  v.u = u;
  return (float)v.h;
}
static __device__ __forceinline__ unsigned int pkf16(float a, float b) {
  union { f16x2 v; unsigned int u; } c;
  c.v = (f16x2){(_Float16)a, (_Float16)b};
  return c.u;
}
static __device__ __forceinline__ void dot2a(float& acc, unsigned int w, unsigned int h) {
  asm volatile("v_dot2_f32_f16 %0, %1, %2, %0" : "+v"(acc) : "v"(w), "v"(h));
}
// LDS-only barrier: does NOT drain vmcnt, so global prefetches stay in flight.
static __device__ __forceinline__ void gbar() {
  __builtin_amdgcn_sched_barrier(0);
  asm volatile("s_waitcnt lgkmcnt(0)" ::: "memory");
  __builtin_amdgcn_s_barrier();
  __builtin_amdgcn_sched_barrier(0);
}

// ---------------------------------------------------------------- prep
__global__ __launch_bounds__(256) void prep_weights(
    const float* __restrict__ item_eb,
    const float* __restrict__ Wg1, const float* __restrict__ Wc1,
    const float* __restrict__ Wg2, const float* __restrict__ Wc2,
    const float* __restrict__ aw1, const float* __restrict__ aw2,
    const float* __restrict__ aw3,
    const float* __restrict__ bg1, const float* __restrict__ bc1,
    const float* __restrict__ bg2, const float* __restrict__ bc2,
    const float* __restrict__ ab1, const float* __restrict__ ab2,
    unsigned short* __restrict__ W1xT, unsigned short* __restrict__ W2xT,
    unsigned short* __restrict__ AW1T, unsigned short* __restrict__ AW2T,
    float* __restrict__ b384_1, float* __restrict__ b384_2,
    float* __restrict__ bA1, float* __restrict__ bA2,
    unsigned int* __restrict__ WgrP1, unsigned int* __restrict__ WguP1,
    unsigned int* __restrict__ WcP1,
    unsigned int* __restrict__ WgrP2, unsigned int* __restrict__ WguP2,
    unsigned int* __restrict__ WcP2,
    float* __restrict__ w3p, unsigned short* __restrict__ Xq,
    float* __restrict__ hstate)
{
  int e = blockIdx.x * 256 + threadIdx.x;
  if (e < 49152) {              // W1xT/W2xT: [384 n][128 k]
    int n = e >> 7, k = e & 127;
    float v1 = (n < 256) ? Wg1[k * 256 + n] : Wc1[k * 128 + (n - 256)];
    float v2 = (n < 256) ? Wg2[k * 256 + n] : Wc2[k * 128 + (n - 256)];
    W1xT[e] = f2bf(v1);
    W2xT[e] = f2bf(v2);
  }
  if (e < 65536) {              // AW1T: [128 n][512 k], pad n>=80
    int n = e >> 9, k = e & 511;
    AW1T[e] = f2bf(n < 80 ? aw1[k * 80 + n] : 0.f);
    Xq[e] = f2bf(item_eb[e]);   // bf16 item_eb [512][128]
    hstate[e] = 0.f;
  }
  if (e < 16384) {              // AW2T: [128 n][128 k]
    int n = e >> 7, k = e & 127;
    AW2T[e] = f2bf((n < 40 && k < 80) ? aw2[k * 40 + n] : 0.f);
  }
  if (e < 8192) {               // GRU h-part weights: [64 i][128 tt], f16 pairs
    int i = e >> 7, tt = e & 127;
    int row = 128 + 2 * i;      // h-dims 2i, 2i+1
    WgrP1[e] = pkf16(Wg1[row * 256 + tt],       Wg1[(row + 1) * 256 + tt]);
    WguP1[e] = pkf16(Wg1[row * 256 + 128 + tt], Wg1[(row + 1) * 256 + 128 + tt]);
    WcP1[e]  = pkf16(Wc1[row * 128 + tt],       Wc1[(row + 1) * 128 + tt]);
    WgrP2[e] = pkf16(Wg2[row * 256 + tt],       Wg2[(row + 1) * 256 + tt]);
    WguP2[e] = pkf16(Wg2[row * 256 + 128 + tt], Wg2[(row + 1) * 256 + 128 + tt]);
    WcP2[e]  = pkf16(Wc2[row * 128 + tt],       Wc2[(row + 1) * 128 + tt]);
  }
  if (e < 384) {
    b384_1[e] = (e < 256) ? bg1[e] : bc1[e - 256];
    b384_2[e] = (e < 256) ? bg2[e] : bc2[e - 256];
  }
  if (e < 128) {
    bA1[e] = (e < 80) ? ab1[e] : 0.f;
    bA2[e] = (e < 40) ? ab2[e] : 0.f;
    w3p[e] = (e < 40) ? aw3[e] : 0.f;
  }
}

// ---------------------------------------------------------------- cast his -> bf16 t-major
__global__ __launch_bounds__(256) void cast_his_t(const float4* __restrict__ in4,
                                                  ushort4* __restrict__ out4)
{
  int i = blockIdx.x * 256 + threadIdx.x;
  float4 v = in4[i];
  int d4 = (i & 31) << 2;
  int bt = i >> 5;
  int tt = bt % 200, bb = bt / 200;
  out4[(((size_t)tt * 512 + bb) * 128 + d4) >> 2] =
      make_ushort4(f2bf(v.x), f2bf(v.y), f2bf(v.z), f2bf(v.w));
}

// ---------------------------------------------------------------- gemm body
// SRC 0: plain bf16 A. SRC 1: din on-the-fly [q|r|q-r|q*r], K=512.
// EPI 0: f16 out (+bias). EPI 1: bf16 sigmoid out. EPI 2: sigmoid+scorer->scores.
struct GemmP {
  const unsigned short* A;
  const unsigned short* B;
  const float* bias;
  unsigned short* out;
  float* scores;
  const float* w3p;
  const float* b3;
  const unsigned short* Xq;
  const unsigned short* rnn1;
  long rowbase;
  int K, ldc, mtiles, tbase;
};

static __device__ __forceinline__ uint4 bfop(uint4 q, uint4 r, bool mul) {
  unsigned short* qs = (unsigned short*)&q;
  unsigned short* rs = (unsigned short*)&r;
  uint4 o;
  unsigned short* os = (unsigned short*)&o;
#pragma unroll
  for (int i = 0; i < 8; i++) {
    float a = bf2f(qs[i]), b = bf2f(rs[i]);
    os[i] = f2bf(mul ? a * b : a - b);
  }
  return o;
}

template <int SRC, int EPI>
__device__ __forceinline__ void gemm_body(const GemmP& P, int tile, char* smem) {
  uint4* AsB = (uint4*)smem;         // 16 KB
  uint4* BsB = AsB + 1024;           // 16 KB
  const int tid = threadIdx.x;
  const int w = tid >> 6, l = tid & 63;
  const int mb = tile % P.mtiles, nb = tile / P.mtiles;
  const long mBase = (long)mb * 128;
  const int nBase = nb * 128;

  f32x4 acc[2][8];
#pragma unroll
  for (int m = 0; m < 2; m++)
#pragma unroll
    for (int n = 0; n < 8; n++) acc[m][n] = 0.f;

  const int srow = (tid >> 3) & 31;
  const int scc = l & 7;
  const int KK = SRC ? 512 : P.K;

  for (int kb = 0; kb < KK; kb += 64) {
#pragma unroll
    for (int p = 0; p < 4; p++) {
      int row = p * 32 + srow;
      long grow = mBase + row;
      uint4 va;
      if (SRC == 0) {
        va = *(const uint4*)(P.A + (size_t)grow * KK + kb + scc * 8);
      } else {
        int seg = kb >> 7;
        int c0 = (kb & 127) + scc * 8;
        int b = (int)(grow & 511);
        if (seg == 0) {
          va = *(const uint4*)(P.Xq + b * 128 + c0);
        } else if (seg == 1) {
          va = *(const uint4*)(P.rnn1 + (size_t)(P.rowbase + grow) * 128 + c0);
        } else {
          uint4 vq = *(const uint4*)(P.Xq + b * 128 + c0);
          uint4 vr = *(const uint4*)(P.rnn1 + (size_t)(P.rowbase + grow) * 128 + c0);
          va = bfop(vq, vr, seg == 3);
        }
      }
      uint4 vb = *(const uint4*)(P.B + (size_t)(nBase + row) * KK + kb + scc * 8);
      AsB[row * 8 + (scc ^ (row & 7))] = va;
      BsB[row * 8 + (scc ^ (row & 7))] = vb;
    }
    __syncthreads();
#pragma unroll
    for (int ks = 0; ks < 2; ks++) {
      int ccr = ks * 4 + (l >> 4);
      int r0 = w * 32 + (l & 15);
      int r1 = r0 + 16;
      bf16x8 a0 = *(const bf16x8*)&AsB[r0 * 8 + (ccr ^ (r0 & 7))];
      bf16x8 a1 = *(const bf16x8*)&AsB[r1 * 8 + (ccr ^ (r1 & 7))];
#pragma unroll
      for (int n = 0; n < 8; n++) {
        int rb = n * 16 + (l & 15);
        bf16x8 bn = *(const bf16x8*)&BsB[rb * 8 + (ccr ^ (rb & 7))];
        acc[0][n] = __builtin_amdgcn_mfma_f32_16x16x32_bf16(a0, bn, acc[0][n], 0, 0, 0);
        acc[1][n] = __builtin_amdgcn_mfma_f32_16x16x32_bf16(a1, bn, acc[1][n], 0, 0, 0);
      }
    }
    __syncthreads();
  }

  const int lcol = l & 15, lrow4 = (l >> 4) * 4;
  if (EPI == 2) {
    float sp[2][4] = {{0.f, 0.f, 0.f, 0.f}, {0.f, 0.f, 0.f, 0.f}};
#pragma unroll
    for (int n = 0; n < 8; n++) {
      int gcol = n * 16 + lcol;
      float bb = P.bias[gcol];
      float w3 = P.w3p[gcol];
#pragma unroll
      for (int m = 0; m < 2; m++)
#pragma unroll
        for (int i = 0; i < 4; i++) {
          float v = acc[m][n][i] + bb;
          sp[m][i] += w3 / (1.f + __expf(-v));
        }
    }
#pragma unroll
    for (int msk = 1; msk < 16; msk <<= 1)
#pragma unroll
      for (int m = 0; m < 2; m++)
#pragma unroll
        for (int i = 0; i < 4; i++) sp[m][i] += __shfl_xor(sp[m][i], msk);
    float b3v = P.b3[0];
    if (lcol == 0) {
#pragma unroll
      for (int m = 0; m < 2; m++)
#pragma unroll
        for (int i = 0; i < 4; i++) {
          long grow = mBase + w * 32 + m * 16 + lrow4 + i;
          int b = (int)(grow & 511);
          int tp = (int)(grow >> 9) + P.tbase;
          P.scores[b * 200 + tp] = sp[m][i] + b3v;
        }
    }
  } else {
#pragma unroll
    for (int n = 0; n < 8; n++) {
      int gcol = nBase + n * 16 + lcol;
      float bb = P.bias[gcol];
#pragma unroll
      for (int m = 0; m < 2; m++)
#pragma unroll
        for (int i = 0; i < 4; i++) {
          long grow = mBase + w * 32 + m * 16 + lrow4 + i;
          float v = acc[m][n][i] + bb;
          if (EPI == 0) P.out[grow * P.ldc + gcol] = f2h(v);
          else          P.out[grow * P.ldc + gcol] = f2bf(1.f / (1.f + __expf(-v)));
        }
    }
  }
}

// ---------------------------------------------------------------- gru body
// 2 rows per 256-thread block: team = t>>7 owns row rblk*2+team; tt = t&127
// owns column tt exclusively (h, u in registers). Zero shuffles; b16 LDS
// exchange of h and r*h; 2 lgkm-only barriers per step; 2-deep x prefetch.
struct GruP {
  const unsigned short* xproj;   // f16 [TC][512][384]
  const unsigned int* Wgr;       // [64][128]
  const unsigned int* Wgu;       // [64][128]
  const unsigned int* Wc;        // [64][128]
  const int* seqlen;
  const float* alphas;
  unsigned short* outbf;         // bf16 [T][512][128] (GRU1 only)
  float* hstate;
  int tbase;
};

template <int AUGRU>
__device__ void gru_body(const GruP& P, int rblk, char* smem) {
  const int t = threadIdx.x;
  const int team = t >> 7, tt = t & 127;
  const int r = rblk * 2 + team;
  const int lenA = P.seqlen[rblk * 2], lenB = P.seqlen[rblk * 2 + 1];
  const int len = team ? lenB : lenA;
  int nsA = lenA - P.tbase; if (nsA > TC) nsA = TC;
  int nsB = lenB - P.tbase; if (nsB > TC) nsB = TC;
  int bsteps = nsA > nsB ? nsA : nsB;

  if (bsteps <= 0) {
    if (!AUGRU) {
      for (int s = 0; s < TC; s++)
        P.outbf[((size_t)(P.tbase + s) * 512 + r) * 128 + tt] = 0;
    }
    return;
  }
  __builtin_amdgcn_s_setprio(1);

  unsigned int wgr[64], wgu[64], wcv[64];
#pragma unroll
  for (int i = 0; i < 64; i++) wgr[i] = P.Wgr[i * 128 + tt];
#pragma unroll
  for (int i = 0; i < 64; i++) wgu[i] = P.Wgu[i * 128 + tt];
#pragma unroll
  for (int i = 0; i < 64; i++) wcv[i] = P.Wc[i * 128 + tt];

  unsigned short* hHh  = (unsigned short*)smem + team * 256;  // 128 halves
  unsigned short* rghH = hHh + 128;                           // 128 halves

  float h = P.hstate[r * 128 + tt];
  hHh[tt] = f2h(h);
  gbar();

  const unsigned short* xp = P.xproj;
  const size_t RS = (size_t)512 * 384;
  const size_t base = (size_t)r * 384;
  unsigned short gR0 = xp[base + tt];
  unsigned short gU0 = xp[base + 128 + tt];
  unsigned short cX0 = xp[base + 256 + tt];
  int s1 = bsteps > 1 ? 1 : 0;
  unsigned short gR1 = xp[s1 * RS + base + tt];
  unsigned short gU1 = xp[s1 * RS + base + 128 + tt];
  unsigned short cX1 = xp[s1 * RS + base + 256 + tt];
  float al0 = AUGRU ? P.alphas[r * 200 + P.tbase] : 0.f;
  float al1 = AUGRU ? P.alphas[r * 200 + P.tbase + s1] : 0.f;

  for (int ts = 0; ts < bsteps; ++ts) {
    int tsn = (ts + 2 < bsteps) ? ts + 2 : bsteps - 1;
    size_t off = (size_t)tsn * RS + base;
    unsigned short gRn = xp[off + tt];
    unsigned short gUn = xp[off + 128 + tt];
    unsigned short cXn = xp[off + 256 + tt];
    float aln = AUGRU ? P.alphas[r * 200 + P.tbase + tsn] : 0.f;

    // ---- phase A: r-gate + u-gate (shared hHh reads, 8 split chains)
    float ar0 = 0.f, ar1 = 0.f, ar2 = 0.f, ar3 = 0.f;
    float au0 = 0.f, au1 = 0.f, au2 = 0.f, au3 = 0.f;
    const uint4* hw = (const uint4*)hHh;
#pragma unroll
    for (int q = 0; q < 4; q++) {
      uint4 h0 = hw[q * 4 + 0];
      uint4 h1 = hw[q * 4 + 1];
      uint4 h2 = hw[q * 4 + 2];
      uint4 h3 = hw[q * 4 + 3];
      dot2a(ar0, wgr[q * 16 + 0], h0.x);  dot2a(au0, wgu[q * 16 + 0], h0.x);
      dot2a(ar1, wgr[q * 16 + 1], h0.y);  dot2a(au1, wgu[q * 16 + 1], h0.y);
      dot2a(ar2, wgr[q * 16 + 2], h0.z);  dot2a(au2, wgu[q * 16 + 2], h0.z);
      dot2a(ar3, wgr[q * 16 + 3], h0.w);  dot2a(au3, wgu[q * 16 + 3], h0.w);
      dot2a(ar0, wgr[q * 16 + 4], h1.x);  dot2a(au0, wgu[q * 16 + 4], h1.x);
      dot2a(ar1, wgr[q * 16 + 5], h1.y);  dot2a(au1, wgu[q * 16 + 5], h1.y);
      dot2a(ar2, wgr[q * 16 + 6], h1.z);  dot2a(au2, wgu[q * 16 + 6], h1.z);
      dot2a(ar3, wgr[q * 16 + 7], h1.w);  dot2a(au3, wgu[q * 16 + 7], h1.w);
      dot2a(ar0, wgr[q * 16 + 8], h2.x);  dot2a(au0, wgu[q * 16 + 8], h2.x);
      dot2a(ar1, wgr[q * 16 + 9], h2.y);  dot2a(au1, wgu[q * 16 + 9], h2.y);
      dot2a(ar2, wgr[q * 16 + 10], h2.z); dot2a(au2, wgu[q * 16 + 10], h2.z);
      dot2a(ar3, wgr[q * 16 + 11], h2.w); dot2a(au3, wgu[q * 16 + 11], h2.w);
      dot2a(ar0, wgr[q * 16 + 12], h3.x); dot2a(au0, wgu[q * 16 + 12], h3.x);
      dot2a(ar1, wgr[q * 16 + 13], h3.y); dot2a(au1, wgu[q * 16 + 13], h3.y);
      dot2a(ar2, wgr[q * 16 + 14], h3.z); dot2a(au2, wgu[q * 16 + 14], h3.z);
      dot2a(ar3, wgr[q * 16 + 15], h3.w); dot2a(au3, wgu[q * 16 + 15], h3.w);
    }
    float ar = (ar0 + ar1) + (ar2 + ar3) + h2f(gR0);
    float au = (au0 + au1) + (au2 + au3) + h2f(gU0);
    float rg = 1.f / (1.f + __expf(-ar));
    float u  = 1.f / (1.f + __expf(-au));
    rghH[tt] = f2h(rg * h);
    gbar();

    // ---- phase B: candidate + update (no shuffles)
    float c0 = 0.f, c1 = 0.f, c2 = 0.f, c3 = 0.f;
    const uint4* rw = (const uint4*)rghH;
#pragma unroll
    for (int q = 0; q < 4; q++) {
      uint4 r0 = rw[q * 4 + 0];
      uint4 r1 = rw[q * 4 + 1];
      uint4 r2 = rw[q * 4 + 2];
      uint4 r3 = rw[q * 4 + 3];
      dot2a(c0, wcv[q * 16 + 0], r0.x);
      dot2a(c1, wcv[q * 16 + 1], r0.y);
      dot2a(c2, wcv[q * 16 + 2], r0.z);
      dot2a(c3, wcv[q * 16 + 3], r0.w);
      dot2a(c0, wcv[q * 16 + 4], r1.x);
      dot2a(c1, wcv[q * 16 + 5], r1.y);
      dot2a(c2, wcv[q * 16 + 6], r1.z);
      dot2a(c3, wcv[q * 16 + 7], r1.w);
      dot2a(c0, wcv[q * 16 + 8], r2.x);
      dot2a(c1, wcv[q * 16 + 9], r2.y);
      dot2a(c2, wcv[q * 16 + 10], r2.z);
      dot2a(c3, wcv[q * 16 + 11], r2.w);
      dot2a(c0, wcv[q * 16 + 12], r3.x);
      dot2a(c1, wcv[q * 16 + 13], r3.y);
      dot2a(c2, wcv[q * 16 + 14], r3.z);
      dot2a(c3, wcv[q * 16 + 15], r3.w);
    }
    float c = (c0 + c1) + (c2 + c3) + h2f(cX0);
    c = fminf(fmaxf(c, -15.f), 15.f);
    float e2 = __expf(2.f * c);
    c = 1.f - 2.f / (e2 + 1.f);          // tanh
    float ue = AUGRU ? u * (1.f - al0) : u;
    float hn = ue * h + (1.f - ue) * c;
    bool valid = (P.tbase + ts) < len;
    h = valid ? hn : h;
    hHh[tt] = f2h(h);
    if (!AUGRU)
      P.outbf[((size_t)(P.tbase + ts) * 512 + r) * 128 + tt] = valid ? f2bf(h) : 0;
    gbar();

    gR0 = gR1; gU0 = gU1; cX0 = cX1; al0 = al1;
    gR1 = gRn; gU1 = gUn; cX1 = cXn; al1 = aln;
  }

  P.hstate[r * 128 + tt] = h;
  if (!AUGRU) {
    for (int s = bsteps; s < TC; s++)
      P.outbf[((size_t)(P.tbase + s) * 512 + r) * 128 + tt] = 0;
  }
}

// ---------------------------------------------------------------- his_sum body
__device__ void hsum_body(const float* __restrict__ his, float* __restrict__ hs,
                          const int* __restrict__ seqlen, int b, char* smem) {
  float* sm = (float*)smem;
  int t = threadIdx.x;
  int len = seqlen[b];
  int col = t & 127, hf = t >> 7;
  float s = 0.f;
  for (int ts = hf; ts < len; ts += 2) s += his[((size_t)b * 200 + ts) * 128 + col];
  sm[t] = s;
  __syncthreads();
  if (t < 128) hs[b * 128 + t] = sm[t] + sm[t + 128];
}

// ---------------------------------------------------------------- fat kernel
template <int AUG, int GRU, int S1, int E1, int S2, int E2, int S3, int E3, int HS>
__global__ __launch_bounds__(256) void fatk(GruP gp, GemmP p1, int c1,
                                            GemmP p2, int c2, GemmP p3,
                                            const float* hisp, float* hsp)
{
  extern __shared__ char smem[];
  int id = blockIdx.x;
  if constexpr (GRU) {
    if (id < 256) { gru_body<AUG>(gp, id, smem); return; }
    id -= 256;
  }
  if constexpr (HS) {
    if (id < 512) { hsum_body(hisp, hsp, gp.seqlen, id, smem); return; }
    id -= 512;
  }
  if constexpr (S1 >= 0) {
    if (id < c1) { gemm_body<S1, E1>(p1, id, smem); return; }
    id -= c1;
  }
  if constexpr (S2 >= 0) {
    if (id < c2) { gemm_body<S2, E2>(p2, id, smem); return; }
    id -= c2;
  }
  if constexpr (S3 >= 0) gemm_body<S3, E3>(p3, id, smem);
}

// ---------------------------------------------------------------- masked softmax (+zero hstate)
__global__ __launch_bounds__(256) void mask_softmax(
    const float* __restrict__ scores, const int* __restrict__ seqlen,
    float* __restrict__ alphas, float* __restrict__ hstate)
{
  int b = blockIdx.x, t = threadIdx.x;
  __shared__ float red[256];
  if (t < 128) hstate[b * 128 + t] = 0.f;
  int len = seqlen[b];
  float s = (t < 200 && t < len) ? scores[b * 200 + t] : -1e30f;
  red[t] = s;
  __syncthreads();
  for (int o = 128; o > 0; o >>= 1) {
    if (t < o) red[t] = fmaxf(red[t], red[t + o]);
    __syncthreads();
  }
  float m = red[0];
  __syncthreads();
  float e = (t < 200 && t < len) ? __expf(s - m) : 0.f;
  red[t] = e;
  __syncthreads();
  for (int o = 128; o > 0; o >>= 1) {
    if (t < o) red[t] += red[t + o];
    __syncthreads();
  }
  float denom = red[0];
  if (t < 200) alphas[b * 200 + t] = e / denom;
}

// ---------------------------------------------------------------- head (his_sum precomputed)
__global__ __launch_bounds__(256) void head_kernel(
    const float* __restrict__ item_eb, const float* __restrict__ hs,
    const float* __restrict__ hstate,
    const float* __restrict__ w1, const float* __restrict__ b1, const float* __restrict__ a1,
    const float* __restrict__ w2, const float* __restrict__ b2, const float* __restrict__ a2,
    const float* __restrict__ w3, const float* __restrict__ b3,
    float* __restrict__ out)
{
  int b = blockIdx.x, t = threadIdx.x;
  __shared__ float frow[512];
  __shared__ float z1[200];
  __shared__ float z2[80];
  if (t < 128) {
    float sv = hs[b * 128 + t];
    float q = item_eb[b * 128 + t];
    frow[t] = q;
    frow[128 + t] = sv;
    frow[256 + t] = q * sv;
    frow[384 + t] = hstate[b * 128 + t];
  }
  __syncthreads();
  if (t < 200) {
    float acc = b1[t];
#pragma unroll 8
    for (int k = 0; k < 512; k++) acc += frow[k] * w1[k * 200 + t];
    z1[t] = acc > 0.f ? acc : a1[t] * acc;
  }
  __syncthreads();
  if (t < 80) {
    float acc = b2[t];
#pragma unroll 8
    for (int k = 0; k < 200; k++) acc += z1[k] * w2[k * 80 + t];
    z2[t] = acc > 0.f ? acc : a2[t] * acc;
  }
  __syncthreads();
  if (t == 0) {
    float l0 = b3[0], l1 = b3[1];
    for (int k = 0; k < 80; k++) {
      float z = z2[k];
      l0 += z * w3[k * 2];
      l1 += z * w3[k * 2 + 1];
    }
    float m = fmaxf(l0, l1);
    float e0 = __expf(l0 - m), e1 = __expf(l1 - m);
    out[b * 2 + 0] = e0 / (e0 + e1);
    out[b * 2 + 1] = e1 / (e0 + e1);
  }
}

// ---------------------------------------------------------------- launch
extern "C" void kernel_launch(void* const* d_in, const int* in_sizes, int n_in,
                              void* d_out, int out_size, void* d_ws, size_t ws_size,
                              hipStream_t stream)
{
  const float* item_eb = (const float*)d_in[0];
  const float* his     = (const float*)d_in[1];
  const float* Wg1     = (const float*)d_in[2];
  const float* bg1     = (const float*)d_in[3];
  const float* Wc1     = (const float*)d_in[4];
  const float* bc1     = (const float*)d_in[5];
  const float* aw1     = (const float*)d_in[6];
  const float* ab1     = (const float*)d_in[7];
  const float* aw2     = (const float*)d_in[8];
  const float* ab2     = (const float*)d_in[9];
  const float* aw3     = (const float*)d_in[10];
  const float* ab3     = (const float*)d_in[11];
  const float* Wg2     = (const float*)d_in[12];
  const float* bg2     = (const float*)d_in[13];
  const float* Wc2     = (const float*)d_in[14];
  const float* bc2     = (const float*)d_in[15];
  const float* fc1w    = (const float*)d_in[16];
  const float* fc1b    = (const float*)d_in[17];
  const float* al1     = (const float*)d_in[18];
  const float* fc2w    = (const float*)d_in[19];
  const float* fc2b    = (const float*)d_in[20];
  const float* al2     = (const float*)d_in[21];
  const float* fc3w    = (const float*)d_in[22];
  const float* fc3b    = (const float*)d_in[23];
  const int*   seqlen  = (const int*)d_in[24];

  // ---- workspace layout (~93.5 MB; round-2 proved >=94.24 MB available)
  char* ws = (char*)d_ws;
  unsigned short* XhA    = (unsigned short*)(ws + 0L);         // 26,214,400 his bf16 t-major; later h1 ring
  unsigned short* xpA    = (unsigned short*)(ws + 26214400L);  // 19,660,800 f16 xproj buf A
  unsigned short* xpB    = (unsigned short*)(ws + 45875200L);  // 19,660,800 f16 xproj buf B
  unsigned short* rnn1   = (unsigned short*)(ws + 65536000L);  // 26,214,400
  float*          scores = (float*)(ws + 91750400L);           //    409,600 (hs after softmax)
  float*          alphas = (float*)(ws + 92160000L);           //    409,600
  float*          hstate = (float*)(ws + 92569600L);           //    262,144
  unsigned int*   WgrP1  = (unsigned int*)(ws + 92831744L);    //     32,768
  unsigned int*   WguP1  = (unsigned int*)(ws + 92864512L);    //     32,768
  unsigned int*   WcP1   = (unsigned int*)(ws + 92897280L);    //     32,768
  unsigned int*   WgrP2  = (unsigned int*)(ws + 92930048L);    //     32,768
  unsigned int*   WguP2  = (unsigned int*)(ws + 92962816L);    //     32,768
  unsigned int*   WcP2   = (unsigned int*)(ws + 92995584L);    //     32,768
  unsigned short* W1xT   = (unsigned short*)(ws + 93028352L);  //     98,304
  unsigned short* W2xT   = (unsigned short*)(ws + 93126656L);  //     98,304
  unsigned short* AW1T   = (unsigned short*)(ws + 93224960L);  //    131,072
  unsigned short* AW2T   = (unsigned short*)(ws + 93356032L);  //     32,768
  float*          b384_1 = (float*)(ws + 93388800L);           //      1,536
  float*          b384_2 = (float*)(ws + 93390336L);           //      1,536
  float*          bA1    = (float*)(ws + 93391872L);           //        512
  float*          bA2    = (float*)(ws + 93392384L);           //        512
  float*          w3p    = (float*)(ws + 93392896L);           //        512
  unsigned short* Xq     = (unsigned short*)(ws + 93393408L);  //    131,072
  float*          hs     = scores;                             // reuse after softmax

  unsigned short* h1[NC] = {XhA, XhA + CSH, XhA + 2 * CSH, XhA + 3 * CSH};

  const int SM = 32768;
  GruP gz{}; GemmP dz{};
  gz.seqlen = seqlen;

  auto mkGru = [&](int c, int aug) {
    GruP g;
    g.xproj = (c & 1) ? xpB : xpA;
    g.Wgr = aug ? WgrP2 : WgrP1;
    g.Wgu = aug ? WguP2 : WguP1;
    g.Wc  = aug ? WcP2  : WcP1;
    g.seqlen = seqlen; g.alphas = alphas;
    g.outbf = aug ? nullptr : rnn1; g.hstate = hstate; g.tbase = c * TC;
    return g;
  };
  auto mkXp = [&](const unsigned short* A, const float* bias, unsigned short* outp) {
    GemmP p{}; p.A = A; p.B = (bias == b384_1) ? W1xT : W2xT; p.bias = bias;
    p.out = outp; p.K = 128; p.ldc = 384; p.mtiles = 200; return p;
  };
  auto mkAtt1 = [&](int c) {
    GemmP p{}; p.B = AW1T; p.bias = bA1; p.out = h1[c];
    p.Xq = Xq; p.rnn1 = rnn1; p.rowbase = (long)c * CROWS;
    p.K = 512; p.ldc = 128; p.mtiles = 200; return p;
  };
  auto mkAtt2 = [&](int c) {
    GemmP p{}; p.A = h1[c]; p.B = AW2T; p.bias = bA2;
    p.scores = scores; p.w3p = w3p; p.b3 = ab3;
    p.K = 128; p.ldc = 128; p.mtiles = 200; p.tbase = c * TC; return p;
  };

  // L1/L2: prep + cast
  prep_weights<<<256, 256, 0, stream>>>(item_eb, Wg1, Wc1, Wg2, Wc2, aw1, aw2, aw3,
                                        bg1, bc1, bg2, bc2, ab1, ab2,
                                        W1xT, W2xT, AW1T, AW2T, b384_1, b384_2, bA1, bA2,
                                        WgrP1, WguP1, WcP1, WgrP2, WguP2, WcP2,
                                        w3p, Xq, hstate);
  cast_his_t<<<12800, 256, 0, stream>>>((const float4*)his, (ushort4*)XhA);

  // L3: xproj1-c0 -> xpA
  fatk<0,0, 0,0, -1,0, -1,0, 0><<<600, 256, SM, stream>>>(
      gz, mkXp(XhA, b384_1, xpA), 600, dz, 0, dz, nullptr, nullptr);
  // L4: gru1-c0 | xproj1-c1 -> xpB
  fatk<0,1, 0,0, -1,0, -1,0, 0><<<856, 256, SM, stream>>>(
      mkGru(0,0), mkXp(XhA + (size_t)CSH, b384_1, xpB), 600, dz, 0, dz, nullptr, nullptr);
  // L5: gru1-c1 | xproj1-c2 -> xpA
  fatk<0,1, 0,0, -1,0, -1,0, 0><<<856, 256, SM, stream>>>(
      mkGru(1,0), mkXp(XhA + (size_t)2*CSH, b384_1, xpA), 600, dz, 0, dz, nullptr, nullptr);
  // L6: gru1-c2 | xproj1-c3 -> xpB | att1-c0 -> h1[0]
  fatk<0,1, 0,0, 1,1, -1,0, 0><<<1056, 256, SM, stream>>>(
      mkGru(2,0), mkXp(XhA + (size_t)3*CSH, b384_1, xpB), 600, mkAtt1(0), 200, dz, nullptr, nullptr);
  // L7: gru1-c3 | att1-c1 | att2-c0
  fatk<0,1, 1,1, 0,2, -1,0, 0><<<656, 256, SM, stream>>>(
      mkGru(3,0), mkAtt1(1), 200, mkAtt2(0), 200, dz, nullptr, nullptr);
  // L8: att1-c2 | att2-c1 | augru-gemm-c0 -> xpA
  fatk<0,0, 1,1, 0,2, 0,0, 0><<<1000, 256, SM, stream>>>(
      gz, mkAtt1(2), 200, mkAtt2(1), 200, mkXp(rnn1, b384_2, xpA), nullptr, nullptr);
  // L9: att1-c3 | att2-c2 | augru-gemm-c1 -> xpB
  fatk<0,0, 1,1, 0,2, 0,0, 0><<<1000, 256, SM, stream>>>(
      gz, mkAtt1(3), 200, mkAtt2(2), 200, mkXp(rnn1 + (size_t)CSH, b384_2, xpB), nullptr, nullptr);
  // L10: att2-c3
  fatk<0,0, 0,2, -1,0, -1,0, 0><<<200, 256, SM, stream>>>(
      gz, mkAtt2(3), 200, dz, 0, dz, nullptr, nullptr);
  // L11: softmax + zero hstate
  mask_softmax<<<512, 256, 0, stream>>>(scores, seqlen, alphas, hstate);
  // L12: augru-c0 | his_sum backfill
  fatk<1,1, -1,0, -1,0, -1,0, 1><<<768, 256, SM, stream>>>(
      mkGru(0,1), dz, 0, dz, 0, dz, his, hs);
  // L13: augru-c1 | augru-gemm-c2 -> xpA
  fatk<1,1, 0,0, -1,0, -1,0, 0><<<856, 256, SM, stream>>>(
      mkGru(1,1), mkXp(rnn1 + (size_t)2*CSH, b384_2, xpA), 600, dz, 0, dz, nullptr, nullptr);
  // L14: augru-c2 | augru-gemm-c3 -> xpB
  fatk<1,1, 0,0, -1,0, -1,0, 0><<<856, 256, SM, stream>>>(
      mkGru(2,1), mkXp(rnn1 + (size_t)3*CSH, b384_2, xpB), 600, dz, 0, dz, nullptr, nullptr);
  // L15: augru-c3
  fatk<1,1, -1,0, -1,0, -1,0, 0><<<256, 256, SM, stream>>>(
      mkGru(3,1), dz, 0, dz, 0, dz, nullptr, nullptr);
  // L16: head
  head_kernel<<<512, 256, 0, stream>>>(item_eb, hs, hstate,
                                       fc1w, fc1b, al1, fc2w, fc2b, al2,
                                       fc3w, fc3b, (float*)d_out);
}